// Round 1
// baseline (895.264 us; speedup 1.0000x reference)
//
#include <hip/hip_runtime.h>
#include <stdint.h>

#define NH 32
#define NKV 8
#define HD 128
#define HID 4096
#define NQKV 6144   // Q_SIZE + 2*KV_SIZE

typedef __attribute__((ext_vector_type(8))) __bf16 bf16x8;
typedef __attribute__((ext_vector_type(4))) float f32x4;
typedef __attribute__((ext_vector_type(4))) float float4v;
typedef __attribute__((ext_vector_type(8))) unsigned short ushort8v;
typedef __attribute__((ext_vector_type(4))) unsigned short ushort4v;
typedef __attribute__((ext_vector_type(2))) unsigned short ushort2v;

__device__ __forceinline__ unsigned short f2bf(float f) {
  union { float f; unsigned u; } x; x.f = f;
  unsigned r = x.u + 0x7fffu + ((x.u >> 16) & 1u);
  return (unsigned short)(r >> 16);
}

__device__ __forceinline__ void gld16(const void* g, void* l) {
  __builtin_amdgcn_global_load_lds(
      (const __attribute__((address_space(1))) unsigned int*)g,
      (__attribute__((address_space(3))) unsigned int*)l, 16, 0, 0);
}

__device__ __forceinline__ f32x4 mfma16(bf16x8 a, bf16x8 b, f32x4 c) {
  return __builtin_amdgcn_mfma_f32_16x16x32_bf16(a, b, c, 0, 0, 0);
}

// ---------------- RoPE table: cos/sin[t][64] (double-precision trig) ------
__global__ void ropetab(const int* __restrict__ pos, float* __restrict__ cosT,
                        float* __restrict__ sinT) {
  const int t = blockIdx.x, f = threadIdx.x;   // 64 threads
  const double inv = exp(-0.2158673524681918 * (double)f);  // ln(1e6)/64
  const double arg = (double)pos[t] * inv;
  cosT[t * 64 + f] = (float)cos(arg);
  sinT[t * 64 + f] = (float)sin(arg);
}

// ---------------- fp32 -> bf16 convert (no transpose) ---------------------
__global__ void convbf(const float* __restrict__ src, unsigned short* __restrict__ dst,
                       long n4) {
  long i = (long)blockIdx.x * blockDim.x + threadIdx.x;
  const long stride = (long)gridDim.x * blockDim.x;
  for (; i < n4; i += stride) {
    float4v v = *(const float4v*)(src + i * 4);
    ushort4v o;
    o.x = f2bf(v.x); o.y = f2bf(v.y); o.z = f2bf(v.z); o.w = f2bf(v.w);
    *(ushort4v*)(dst + i * 4) = o;
  }
}

// ------------- weight transpose+convert: W (K x N f32) -> Wt (N x K bf16) --
__global__ __launch_bounds__(256) void wtrans(const float* __restrict__ W,
                                              unsigned short* __restrict__ Wt,
                                              int K, int N) {
  __shared__ float tile[64][65];
  const int k0 = blockIdx.y * 64, n0 = blockIdx.x * 64;
  const int tid = threadIdx.x;
  const int rk = tid >> 4, cn = (tid & 15) * 4;
#pragma unroll
  for (int rr = 0; rr < 64; rr += 16) {
    float4v v = *(const float4v*)(W + (long)(k0 + rk + rr) * N + n0 + cn);
    tile[rk + rr][cn] = v.x; tile[rk + rr][cn + 1] = v.y;
    tile[rk + rr][cn + 2] = v.z; tile[rk + rr][cn + 3] = v.w;
  }
  __syncthreads();
  const int rn = tid >> 3, ck = (tid & 7) * 8;
#pragma unroll
  for (int rr = 0; rr < 64; rr += 32) {
    ushort8v o;
#pragma unroll
    for (int j = 0; j < 8; ++j) o[j] = f2bf(tile[ck + j][rn + rr]);
    *(ushort8v*)(Wt + (long)(n0 + rn + rr) * K + k0 + ck) = o;
  }
}

// ------------- V transpose: qkv f32 rows -> Vt[kvh][d][t] bf16 ------------
__global__ __launch_bounds__(256) void vtrans(const float* __restrict__ qkv,
                                              unsigned short* __restrict__ Vt, int T) {
  __shared__ float tile[64][65];
  const int kvh = blockIdx.z;
  const int t0 = blockIdx.x * 64, d0 = blockIdx.y * 64;
  const int tid = threadIdx.x;
  const int rt = tid >> 4, cd = (tid & 15) * 4;
#pragma unroll
  for (int rr = 0; rr < 64; rr += 16) {
    float4v v = *(const float4v*)(qkv + (long)(t0 + rt + rr) * NQKV + 5120 + kvh * 128 + d0 + cd);
    tile[rt + rr][cd] = v.x; tile[rt + rr][cd + 1] = v.y;
    tile[rt + rr][cd + 2] = v.z; tile[rt + rr][cd + 3] = v.w;
  }
  __syncthreads();
  const int rd = tid >> 3, ct = (tid & 7) * 8;
#pragma unroll
  for (int rr = 0; rr < 64; rr += 32) {
    ushort8v o;
#pragma unroll
    for (int j = 0; j < 8; ++j) o[j] = f2bf(tile[ct + j][rd + rr]);
    *(ushort8v*)(Vt + ((long)kvh * 128 + d0 + rd + rr) * T + t0 + ct) = o;
  }
}

// ------------- RMSNorm + RoPE: qkv f32 -> Q/K bf16 ------------------------
__global__ __launch_bounds__(256) void norm_rope(
    const float* __restrict__ qkv, const float* __restrict__ qw,
    const float* __restrict__ kw, const float* __restrict__ cosT,
    const float* __restrict__ sinT, unsigned short* __restrict__ Qo,
    unsigned short* __restrict__ Ko, int T, int ctx, int noise) {
  const int t = blockIdx.x;
  __shared__ float cs[64], sn[64];
  const int tid = threadIdx.x;
  if (tid < 64) { cs[tid] = cosT[t * 64 + tid]; sn[tid] = sinT[t * 64 + tid]; }
  __syncthreads();
  const int wid = tid >> 6, lane = tid & 63;
  const float* row = qkv + (long)t * NQKV;
  const bool isNoise = (t >= ctx);
  for (int sl = wid; sl < 40; sl += 4) {      // slots: 0-31 q heads, 32-39 k heads
    if (sl < 32 && !isNoise) continue;
    const float* x = row + sl * 128;
    float v0 = x[lane * 2], v1 = x[lane * 2 + 1];
    float ss = v0 * v0 + v1 * v1;
#pragma unroll
    for (int off = 32; off >= 1; off >>= 1) ss += __shfl_xor(ss, off);
    const float rinv = rsqrtf(ss * (1.f / 128.f) + 1e-6f);
    const float* w = (sl < 32) ? qw : kw;
    v0 *= rinv * w[lane * 2];
    v1 *= rinv * w[lane * 2 + 1];
    const float p0 = __shfl_xor(v0, 32);
    const float p1 = __shfl_xor(v1, 32);
    const int f0 = (lane * 2) & 63, f1 = (lane * 2 + 1) & 63;
    float o0, o1;
    if (lane < 32) { o0 = v0 * cs[f0] - p0 * sn[f0]; o1 = v1 * cs[f1] - p1 * sn[f1]; }
    else           { o0 = v0 * cs[f0] + p0 * sn[f0]; o1 = v1 * cs[f1] + p1 * sn[f1]; }
    ushort2v o; o.x = f2bf(o0); o.y = f2bf(o1);
    if (sl < 32)
      *(ushort2v*)(Qo + ((long)sl * noise + (t - ctx)) * 128 + lane * 2) = o;
    else
      *(ushort2v*)(Ko + ((long)(sl - 32) * T + t) * 128 + lane * 2) = o;
  }
}

// ------------- m97-style bf16 GEMM: C = A @ Bt^T (+bias) ------------------
// A: M x K bf16, Bt: N x K bf16, C: M x N f32
__global__ __launch_bounds__(256) void gemm_bt(
    const unsigned short* __restrict__ A, const unsigned short* __restrict__ Bt,
    float* __restrict__ C, const float* __restrict__ bias, int M, int N, int K) {
  __shared__ unsigned short As[128 * 32];
  __shared__ unsigned short Bs[128 * 32];
  const int tid = threadIdx.x;
  const int wid = tid >> 6, lane = tid & 63;
  const int lr = lane & 15, lg = lane >> 4;
  const long bm = (long)blockIdx.y * 128;
  const long bn = (long)blockIdx.x * 128;
  const int wm = (wid >> 1) * 64;
  const int wn = (wid & 1) * 64;
  f32x4 acc[4][4] = {};
  for (int k0 = 0; k0 < K; k0 += 32) {
#pragma unroll
    for (int c = 0; c < 2; ++c) {
      const int q = c * 4 + wid;
      const int idx = q * 64 + lane;
      const int r = idx >> 2;
      const int ce = (idx & 3) * 8;
      gld16(A + (bm + r) * (long)K + k0 + ce, As + q * 512);
      gld16(Bt + (bn + r) * (long)K + k0 + ce, Bs + q * 512);
    }
    __syncthreads();
    bf16x8 af[4], bfv[4];
#pragma unroll
    for (int i = 0; i < 4; ++i) {
      af[i]  = *(const bf16x8*)(As + (wm + i * 16 + lr) * 32 + lg * 8);
      bfv[i] = *(const bf16x8*)(Bs + (wn + i * 16 + lr) * 32 + lg * 8);
    }
#pragma unroll
    for (int i = 0; i < 4; ++i)
#pragma unroll
      for (int j = 0; j < 4; ++j)
        acc[i][j] = mfma16(af[i], bfv[j], acc[i][j]);
    __syncthreads();
  }
#pragma unroll
  for (int i = 0; i < 4; ++i) {
#pragma unroll
    for (int j = 0; j < 4; ++j) {
      const long row = bm + wm + i * 16 + lg * 4;
      const long col = bn + wn + j * 16 + lr;
      const float b = bias ? bias[col] : 0.f;
#pragma unroll
      for (int r = 0; r < 4; ++r)
        C[(row + r) * (long)N + col] = acc[i][j][r] + b;
    }
  }
}

// ------------- flash attention (GQA, full non-causal) ---------------------
// Q: [NH][noise][128], K: [NKV][T][128], Vt: [NKV][128][T], O: [noise][4096] bf16
__global__ __launch_bounds__(256) void attn_kernel(
    const unsigned short* __restrict__ Q, const unsigned short* __restrict__ Kb,
    const unsigned short* __restrict__ Vt, unsigned short* __restrict__ Oout,
    int noise, int T, float scale) {
  __shared__ unsigned short Ks[64 * 128];   // [t][d]
  __shared__ unsigned short Vs[128 * 64];   // [d][t]
  __shared__ unsigned short Ps[4 * 16 * 64];
  const int h = blockIdx.y;
  const int kvh = h >> 2;
  const int tid = threadIdx.x, wid = tid >> 6, lane = tid & 63;
  const int lr = lane & 15, lg = lane >> 4;
  const unsigned short* qb = Q + ((long)h * noise + blockIdx.x * 64 + wid * 16 + lr) * 128;
  bf16x8 qf[4];
#pragma unroll
  for (int kc = 0; kc < 4; ++kc) qf[kc] = *(const bf16x8*)(qb + kc * 32 + lg * 8);
  const unsigned short* kbase = Kb + (long)kvh * T * 128;
  const unsigned short* vbase = Vt + (long)kvh * 128 * T;
  f32x4 accO[8] = {};
  float m_r[4], l_r[4];
#pragma unroll
  for (int r = 0; r < 4; ++r) { m_r[r] = -1e30f; l_r[r] = 0.f; }
  unsigned short* pw = Ps + wid * 1024;
  for (int t0 = 0; t0 < T; t0 += 64) {
#pragma unroll
    for (int c = 0; c < 4; ++c) {
      const int q = c * 4 + wid;
      const int idx = q * 64 + lane;
      gld16(kbase + (long)t0 * 128 + idx * 8, Ks + q * 512);
      const int d = idx >> 3, tb = (idx & 7) * 8;
      gld16(vbase + (long)d * T + t0 + tb, Vs + q * 512);
    }
    __syncthreads();
    f32x4 s[4] = {};
#pragma unroll
    for (int kc = 0; kc < 4; ++kc)
#pragma unroll
      for (int nt = 0; nt < 4; ++nt) {
        bf16x8 kf = *(const bf16x8*)(Ks + (nt * 16 + lr) * 128 + kc * 32 + lg * 8);
        s[nt] = mfma16(qf[kc], kf, s[nt]);
      }
#pragma unroll
    for (int nt = 0; nt < 4; ++nt)
#pragma unroll
      for (int r = 0; r < 4; ++r) s[nt][r] *= scale;
    float mt[4], rs[4];
#pragma unroll
    for (int r = 0; r < 4; ++r)
      mt[r] = fmaxf(fmaxf(s[0][r], s[1][r]), fmaxf(s[2][r], s[3][r]));
#pragma unroll
    for (int off = 8; off >= 1; off >>= 1)
#pragma unroll
      for (int r = 0; r < 4; ++r) mt[r] = fmaxf(mt[r], __shfl_xor(mt[r], off));
    float corr[4];
#pragma unroll
    for (int r = 0; r < 4; ++r) {
      const float mn = fmaxf(m_r[r], mt[r]);
      corr[r] = __expf(m_r[r] - mn);
      m_r[r] = mn;
      rs[r] = 0.f;
    }
#pragma unroll
    for (int nt = 0; nt < 4; ++nt)
#pragma unroll
      for (int r = 0; r < 4; ++r) {
        const float p = __expf(s[nt][r] - m_r[r]);
        s[nt][r] = p;
        rs[r] += p;
      }
#pragma unroll
    for (int off = 8; off >= 1; off >>= 1)
#pragma unroll
      for (int r = 0; r < 4; ++r) rs[r] += __shfl_xor(rs[r], off);
#pragma unroll
    for (int r = 0; r < 4; ++r) l_r[r] = l_r[r] * corr[r] + rs[r];
#pragma unroll
    for (int nd = 0; nd < 8; ++nd)
#pragma unroll
      for (int r = 0; r < 4; ++r) accO[nd][r] *= corr[r];
#pragma unroll
    for (int nt = 0; nt < 4; ++nt)
#pragma unroll
      for (int r = 0; r < 4; ++r)
        pw[(lg * 4 + r) * 64 + nt * 16 + lr] = f2bf(s[nt][r]);
    __syncthreads();   // P visible (and keeps waves in lockstep before PV)
#pragma unroll
    for (int kc = 0; kc < 2; ++kc) {
      bf16x8 pa = *(const bf16x8*)(pw + lr * 64 + kc * 32 + lg * 8);
#pragma unroll
      for (int nd = 0; nd < 8; ++nd) {
        bf16x8 vf = *(const bf16x8*)(Vs + (nd * 16 + lr) * 64 + kc * 32 + lg * 8);
        accO[nd] = mfma16(pa, vf, accO[nd]);
      }
    }
    __syncthreads();
  }
  float inv[4];
#pragma unroll
  for (int r = 0; r < 4; ++r) inv[r] = 1.f / l_r[r];
  const long orow = (long)blockIdx.x * 64 + wid * 16;
#pragma unroll
  for (int nd = 0; nd < 8; ++nd)
#pragma unroll
    for (int r = 0; r < 4; ++r)
      Oout[(orow + lg * 4 + r) * 4096 + h * 128 + nd * 16 + lr] =
          f2bf(accO[nd][r] * inv[r]);
}

extern "C" void kernel_launch(void* const* d_in, const int* in_sizes, int n_in,
                              void* d_out, int out_size, void* d_ws, size_t ws_size,
                              hipStream_t stream) {
  const int*   positions = (const int*)d_in[0];
  const float* hidden    = (const float*)d_in[1];
  const float* w_qkv     = (const float*)d_in[3];
  const float* b_qkv     = (const float*)d_in[4];
  const float* q_norm_w  = (const float*)d_in[5];
  const float* k_norm_w  = (const float*)d_in[6];
  const float* w_o       = (const float*)d_in[7];
  float* out = (float*)d_out;
  const int T = in_sizes[0];
  const int noise = out_size / HID;
  const int ctx = T - noise;

  char* ws = (char*)d_ws;
  // layout (with aliasing): qkv_f32 [T*6144 f32] (later reused as attn_out bf16)
  float* qkv_f32 = (float*)ws;
  unsigned short* attn_out = (unsigned short*)ws;           // alias, used after qkv dead
  size_t off = (size_t)T * NQKV * 4;
  unsigned short* Hbf = (unsigned short*)(ws + off);        // T*HID bf16
  unsigned short* WoT = Hbf;                                // alias, written after QKV GEMM
  off += (size_t)T * HID * 2;
  unsigned short* WqkvT = (unsigned short*)(ws + off);      // NQKV*HID bf16
  off += (size_t)NQKV * HID * 2;
  float* cosT = (float*)(ws + off); off += (size_t)T * 64 * 4;
  float* sinT = (float*)(ws + off); off += (size_t)T * 64 * 4;
  unsigned short* Qb  = (unsigned short*)(ws + off); off += (size_t)NH * noise * HD * 2;
  unsigned short* Kbf = (unsigned short*)(ws + off); off += (size_t)NKV * T * HD * 2;
  unsigned short* Vtb = (unsigned short*)(ws + off); off += (size_t)NKV * HD * T * 2;

  ropetab<<<dim3(T), dim3(64), 0, stream>>>(positions, cosT, sinT);
  convbf<<<dim3(2048), dim3(256), 0, stream>>>(hidden, Hbf, (long)T * HID / 4);
  wtrans<<<dim3(NQKV / 64, HID / 64), dim3(256), 0, stream>>>(w_qkv, WqkvT, HID, NQKV);
  gemm_bt<<<dim3(NQKV / 128, T / 128), dim3(256), 0, stream>>>(Hbf, WqkvT, qkv_f32, b_qkv, T, NQKV, HID);
  wtrans<<<dim3(HID / 64, HID / 64), dim3(256), 0, stream>>>(w_o, WoT, HID, HID);
  norm_rope<<<dim3(T), dim3(256), 0, stream>>>(qkv_f32, q_norm_w, k_norm_w, cosT, sinT, Qb, Kbf, T, ctx, noise);
  vtrans<<<dim3(T / 64, HD / 64, NKV), dim3(256), 0, stream>>>(qkv_f32, Vtb, T);
  const float scale = 0.08838834764831845f;  // HD^-0.5
  attn_kernel<<<dim3(noise / 64, NH), dim3(256), 0, stream>>>(Qb, Kbf, Vtb, attn_out, noise, T, scale);
  gemm_bt<<<dim3(HID / 128, noise / 128), dim3(256), 0, stream>>>(attn_out, WoT, out, (const float*)nullptr, noise, HID, HID);
}

// Round 2
// 803.616 us; speedup vs baseline: 1.1140x; 1.1140x over previous
//
#include <hip/hip_runtime.h>
#include <stdint.h>

#define NH 32
#define NKV 8
#define HD 128
#define HID 4096
#define NQKV 6144   // Q_SIZE + 2*KV_SIZE

typedef __attribute__((ext_vector_type(8))) __bf16 bf16x8;
typedef __attribute__((ext_vector_type(4))) float f32x4;
typedef __attribute__((ext_vector_type(4))) float float4v;
typedef __attribute__((ext_vector_type(8))) unsigned short ushort8v;
typedef __attribute__((ext_vector_type(4))) unsigned short ushort4v;
typedef __attribute__((ext_vector_type(2))) unsigned short ushort2v;

__device__ __forceinline__ unsigned short f2bf(float f) {
  union { float f; unsigned u; } x; x.f = f;
  unsigned r = x.u + 0x7fffu + ((x.u >> 16) & 1u);
  return (unsigned short)(r >> 16);
}

__device__ __forceinline__ void gld16(const void* g, void* l) {
  __builtin_amdgcn_global_load_lds(
      (const __attribute__((address_space(1))) unsigned int*)g,
      (__attribute__((address_space(3))) unsigned int*)l, 16, 0, 0);
}

__device__ __forceinline__ f32x4 mfma16(bf16x8 a, bf16x8 b, f32x4 c) {
  return __builtin_amdgcn_mfma_f32_16x16x32_bf16(a, b, c, 0, 0, 0);
}

// ---------------- RoPE table: cos/sin[t][64] (double-precision trig) ------
__global__ void ropetab(const int* __restrict__ pos, float* __restrict__ cosT,
                        float* __restrict__ sinT) {
  const int t = blockIdx.x, f = threadIdx.x;   // 64 threads
  const double inv = exp(-0.2158673524681918 * (double)f);  // ln(1e6)/64
  const double arg = (double)pos[t] * inv;
  cosT[t * 64 + f] = (float)cos(arg);
  sinT[t * 64 + f] = (float)sin(arg);
}

// ---------------- fp32 -> bf16 convert (no transpose) ---------------------
__global__ void convbf(const float* __restrict__ src, unsigned short* __restrict__ dst,
                       long n4) {
  long i = (long)blockIdx.x * blockDim.x + threadIdx.x;
  const long stride = (long)gridDim.x * blockDim.x;
  for (; i < n4; i += stride) {
    float4v v = *(const float4v*)(src + i * 4);
    ushort4v o;
    o.x = f2bf(v.x); o.y = f2bf(v.y); o.z = f2bf(v.z); o.w = f2bf(v.w);
    *(ushort4v*)(dst + i * 4) = o;
  }
}

// ------------- weight transpose+convert: W (K x N f32) -> Wt (N x K bf16) --
__global__ __launch_bounds__(256) void wtrans(const float* __restrict__ W,
                                              unsigned short* __restrict__ Wt,
                                              int K, int N) {
  __shared__ float tile[64][65];
  const int k0 = blockIdx.y * 64, n0 = blockIdx.x * 64;
  const int tid = threadIdx.x;
  const int rk = tid >> 4, cn = (tid & 15) * 4;
#pragma unroll
  for (int rr = 0; rr < 64; rr += 16) {
    float4v v = *(const float4v*)(W + (long)(k0 + rk + rr) * N + n0 + cn);
    tile[rk + rr][cn] = v.x; tile[rk + rr][cn + 1] = v.y;
    tile[rk + rr][cn + 2] = v.z; tile[rk + rr][cn + 3] = v.w;
  }
  __syncthreads();
  const int rn = tid >> 3, ck = (tid & 7) * 8;
#pragma unroll
  for (int rr = 0; rr < 64; rr += 32) {
    ushort8v o;
#pragma unroll
    for (int j = 0; j < 8; ++j) o[j] = f2bf(tile[ck + j][rn + rr]);
    *(ushort8v*)(Wt + (long)(n0 + rn + rr) * K + k0 + ck) = o;
  }
}

// ------------- V transpose: qkv f32 rows -> Vt[kvh][d][t] bf16 ------------
__global__ __launch_bounds__(256) void vtrans(const float* __restrict__ qkv,
                                              unsigned short* __restrict__ Vt, int T) {
  __shared__ float tile[64][65];
  const int kvh = blockIdx.z;
  const int t0 = blockIdx.x * 64, d0 = blockIdx.y * 64;
  const int tid = threadIdx.x;
  const int rt = tid >> 4, cd = (tid & 15) * 4;
#pragma unroll
  for (int rr = 0; rr < 64; rr += 16) {
    float4v v = *(const float4v*)(qkv + (long)(t0 + rt + rr) * NQKV + 5120 + kvh * 128 + d0 + cd);
    tile[rt + rr][cd] = v.x; tile[rt + rr][cd + 1] = v.y;
    tile[rt + rr][cd + 2] = v.z; tile[rt + rr][cd + 3] = v.w;
  }
  __syncthreads();
  const int rd = tid >> 3, ct = (tid & 7) * 8;
#pragma unroll
  for (int rr = 0; rr < 64; rr += 32) {
    ushort8v o;
#pragma unroll
    for (int j = 0; j < 8; ++j) o[j] = f2bf(tile[ct + j][rd + rr]);
    *(ushort8v*)(Vt + ((long)kvh * 128 + d0 + rd + rr) * T + t0 + ct) = o;
  }
}

// ------------- RMSNorm + RoPE: qkv f32 -> Q/K bf16 ------------------------
__global__ __launch_bounds__(256) void norm_rope(
    const float* __restrict__ qkv, const float* __restrict__ qw,
    const float* __restrict__ kw, const float* __restrict__ cosT,
    const float* __restrict__ sinT, unsigned short* __restrict__ Qo,
    unsigned short* __restrict__ Ko, int T, int ctx, int noise) {
  const int t = blockIdx.x;
  __shared__ float cs[64], sn[64];
  const int tid = threadIdx.x;
  if (tid < 64) { cs[tid] = cosT[t * 64 + tid]; sn[tid] = sinT[t * 64 + tid]; }
  __syncthreads();
  const int wid = tid >> 6, lane = tid & 63;
  const float* row = qkv + (long)t * NQKV;
  const bool isNoise = (t >= ctx);
  for (int sl = wid; sl < 40; sl += 4) {      // slots: 0-31 q heads, 32-39 k heads
    if (sl < 32 && !isNoise) continue;
    const float* x = row + sl * 128;
    float v0 = x[lane * 2], v1 = x[lane * 2 + 1];
    float ss = v0 * v0 + v1 * v1;
#pragma unroll
    for (int off = 32; off >= 1; off >>= 1) ss += __shfl_xor(ss, off);
    const float rinv = rsqrtf(ss * (1.f / 128.f) + 1e-6f);
    const float* w = (sl < 32) ? qw : kw;
    v0 *= rinv * w[lane * 2];
    v1 *= rinv * w[lane * 2 + 1];
    const float p0 = __shfl_xor(v0, 32);
    const float p1 = __shfl_xor(v1, 32);
    const int f0 = (lane * 2) & 63, f1 = (lane * 2 + 1) & 63;
    float o0, o1;
    if (lane < 32) { o0 = v0 * cs[f0] - p0 * sn[f0]; o1 = v1 * cs[f1] - p1 * sn[f1]; }
    else           { o0 = v0 * cs[f0] + p0 * sn[f0]; o1 = v1 * cs[f1] + p1 * sn[f1]; }
    ushort2v o; o.x = f2bf(o0); o.y = f2bf(o1);
    if (sl < 32)
      *(ushort2v*)(Qo + ((long)sl * noise + (t - ctx)) * 128 + lane * 2) = o;
    else
      *(ushort2v*)(Ko + ((long)(sl - 32) * T + t) * 128 + lane * 2) = o;
  }
}

// ------------- m97-style bf16 GEMM: C = A @ Bt^T (+bias), optional split-K -
// A: M x K bf16, Bt: N x K bf16, C: M x N f32
// gridDim.z = split-K factor; if >1, epilogue atomicAdds (C must be zeroed).
__global__ __launch_bounds__(256) void gemm_bt(
    const unsigned short* __restrict__ A, const unsigned short* __restrict__ Bt,
    float* __restrict__ C, const float* __restrict__ bias, int M, int N, int K) {
  __shared__ unsigned short As[128 * 32];
  __shared__ unsigned short Bs[128 * 32];
  const int tid = threadIdx.x;
  const int wid = tid >> 6, lane = tid & 63;
  const int lr = lane & 15, lg = lane >> 4;
  const long bm = (long)blockIdx.y * 128;
  const long bn = (long)blockIdx.x * 128;
  const int wm = (wid >> 1) * 64;
  const int wn = (wid & 1) * 64;
  const int nz = gridDim.z;
  const int kLen = K / nz;
  const int kOff = blockIdx.z * kLen;
  f32x4 acc[4][4] = {};
  for (int k0 = kOff; k0 < kOff + kLen; k0 += 32) {
#pragma unroll
    for (int c = 0; c < 2; ++c) {
      const int q = c * 4 + wid;
      const int idx = q * 64 + lane;
      const int r = idx >> 2;
      const int ce = (idx & 3) * 8;
      gld16(A + (bm + r) * (long)K + k0 + ce, As + q * 512);
      gld16(Bt + (bn + r) * (long)K + k0 + ce, Bs + q * 512);
    }
    __syncthreads();
    bf16x8 af[4], bfv[4];
#pragma unroll
    for (int i = 0; i < 4; ++i) {
      af[i]  = *(const bf16x8*)(As + (wm + i * 16 + lr) * 32 + lg * 8);
      bfv[i] = *(const bf16x8*)(Bs + (wn + i * 16 + lr) * 32 + lg * 8);
    }
#pragma unroll
    for (int i = 0; i < 4; ++i)
#pragma unroll
      for (int j = 0; j < 4; ++j)
        acc[i][j] = mfma16(af[i], bfv[j], acc[i][j]);
    __syncthreads();
  }
  if (nz == 1) {
#pragma unroll
    for (int i = 0; i < 4; ++i) {
#pragma unroll
      for (int j = 0; j < 4; ++j) {
        const long row = bm + wm + i * 16 + lg * 4;
        const long col = bn + wn + j * 16 + lr;
        const float b = bias ? bias[col] : 0.f;
#pragma unroll
        for (int r = 0; r < 4; ++r)
          C[(row + r) * (long)N + col] = acc[i][j][r] + b;
      }
    }
  } else {
#pragma unroll
    for (int i = 0; i < 4; ++i) {
#pragma unroll
      for (int j = 0; j < 4; ++j) {
        const long row = bm + wm + i * 16 + lg * 4;
        const long col = bn + wn + j * 16 + lr;
#pragma unroll
        for (int r = 0; r < 4; ++r)
          atomicAdd(&C[(row + r) * (long)N + col], acc[i][j][r]);
      }
    }
  }
}

// ------------- flash attention (GQA, full non-causal) ---------------------
// Q: [NH][noise][128], K: [NKV][T][128], Vt: [NKV][128][T], O: [noise][4096] bf16
// All LDS tiles XOR-swizzled: logical 16B chunk c in row r lives at c^(r&7).
// Staging keeps LDS dest linear (global_load_lds constraint) and pre-swizzles
// the per-lane GLOBAL source chunk instead (guide rule #21).
__global__ __launch_bounds__(256) void attn_kernel(
    const unsigned short* __restrict__ Q, const unsigned short* __restrict__ Kb,
    const unsigned short* __restrict__ Vt, unsigned short* __restrict__ Oout,
    int noise, int T, float scale) {
  __shared__ unsigned short Ks[64 * 128];   // [t][d], 256B rows, swizzled
  __shared__ unsigned short Vs[128 * 64];   // [d][t], 128B rows, swizzled
  __shared__ unsigned short Ps[4 * 16 * 64];// per-wave [16][64], swizzled
  const int h = blockIdx.y;
  const int kvh = h >> 2;
  const int tid = threadIdx.x, wid = tid >> 6, lane = tid & 63;
  const int lr = lane & 15, lg = lane >> 4;
  const unsigned short* qb = Q + ((long)h * noise + blockIdx.x * 64 + wid * 16 + lr) * 128;
  bf16x8 qf[4];
#pragma unroll
  for (int kc = 0; kc < 4; ++kc) qf[kc] = *(const bf16x8*)(qb + kc * 32 + lg * 8);
  const unsigned short* kbase = Kb + (long)kvh * T * 128;
  const unsigned short* vbase = Vt + (long)kvh * 128 * T;
  f32x4 accO[8] = {};
  float m_r[4], l_r[4];
#pragma unroll
  for (int r = 0; r < 4; ++r) { m_r[r] = -1e30f; l_r[r] = 0.f; }
  unsigned short* pw = Ps + wid * 1024;
  const int sw = (lr & 7) << 3;             // read-side XOR (shorts)
  for (int t0 = 0; t0 < T; t0 += 64) {
#pragma unroll
    for (int c = 0; c < 4; ++c) {
      const int q = c * 4 + wid;
      const int idx = q * 64 + lane;
      // K: rows of 16 chunks; swizzle low 3 bits of chunk-in-row by row&7
      const int kgi = (idx & ~7) | ((idx ^ (idx >> 4)) & 7);
      gld16(kbase + (long)t0 * 128 + (long)kgi * 8, Ks + q * 512);
      // V: rows of 8 chunks; swizzle chunk-in-row by row&7
      const int d = idx >> 3;
      const int cg = (idx ^ d) & 7;
      gld16(vbase + (long)d * T + t0 + cg * 8, Vs + q * 512);
    }
    __syncthreads();
    f32x4 s[4] = {};
    __builtin_amdgcn_s_setprio(1);
#pragma unroll
    for (int kc = 0; kc < 4; ++kc)
#pragma unroll
      for (int nt = 0; nt < 4; ++nt) {
        bf16x8 kf = *(const bf16x8*)(Ks + (nt * 16 + lr) * 128 + (((kc * 32) + lg * 8) ^ sw));
        s[nt] = mfma16(qf[kc], kf, s[nt]);
      }
    __builtin_amdgcn_s_setprio(0);
#pragma unroll
    for (int nt = 0; nt < 4; ++nt)
#pragma unroll
      for (int r = 0; r < 4; ++r) s[nt][r] *= scale;
    float mt[4], rs[4];
#pragma unroll
    for (int r = 0; r < 4; ++r)
      mt[r] = fmaxf(fmaxf(s[0][r], s[1][r]), fmaxf(s[2][r], s[3][r]));
#pragma unroll
    for (int off = 8; off >= 1; off >>= 1)
#pragma unroll
      for (int r = 0; r < 4; ++r) mt[r] = fmaxf(mt[r], __shfl_xor(mt[r], off));
    float corr[4];
#pragma unroll
    for (int r = 0; r < 4; ++r) {
      const float mn = fmaxf(m_r[r], mt[r]);
      corr[r] = __expf(m_r[r] - mn);
      m_r[r] = mn;
      rs[r] = 0.f;
    }
#pragma unroll
    for (int nt = 0; nt < 4; ++nt)
#pragma unroll
      for (int r = 0; r < 4; ++r) {
        const float p = __expf(s[nt][r] - m_r[r]);
        s[nt][r] = p;
        rs[r] += p;
      }
#pragma unroll
    for (int off = 8; off >= 1; off >>= 1)
#pragma unroll
      for (int r = 0; r < 4; ++r) rs[r] += __shfl_xor(rs[r], off);
#pragma unroll
    for (int r = 0; r < 4; ++r) l_r[r] = l_r[r] * corr[r] + rs[r];
#pragma unroll
    for (int nd = 0; nd < 8; ++nd)
#pragma unroll
      for (int r = 0; r < 4; ++r) accO[nd][r] *= corr[r];
#pragma unroll
    for (int nt = 0; nt < 4; ++nt)
#pragma unroll
      for (int r = 0; r < 4; ++r) {
        const int prow = lg * 4 + r;
        pw[prow * 64 + ((nt * 16 + lr) ^ ((prow & 7) << 3))] = f2bf(s[nt][r]);
      }
    __syncthreads();   // P visible (and keeps waves in lockstep before PV)
    __builtin_amdgcn_s_setprio(1);
#pragma unroll
    for (int kc = 0; kc < 2; ++kc) {
      bf16x8 pa = *(const bf16x8*)(pw + lr * 64 + (((kc * 32) + lg * 8) ^ sw));
#pragma unroll
      for (int nd = 0; nd < 8; ++nd) {
        bf16x8 vf = *(const bf16x8*)(Vs + (nd * 16 + lr) * 64 + (((kc * 32) + lg * 8) ^ sw));
        accO[nd] = mfma16(pa, vf, accO[nd]);
      }
    }
    __builtin_amdgcn_s_setprio(0);
    __syncthreads();
  }
  float inv[4];
#pragma unroll
  for (int r = 0; r < 4; ++r) inv[r] = 1.f / l_r[r];
  const long orow = (long)blockIdx.x * 64 + wid * 16;
#pragma unroll
  for (int nd = 0; nd < 8; ++nd)
#pragma unroll
    for (int r = 0; r < 4; ++r)
      Oout[(orow + lg * 4 + r) * 4096 + h * 128 + nd * 16 + lr] =
          f2bf(accO[nd][r] * inv[r]);
}

extern "C" void kernel_launch(void* const* d_in, const int* in_sizes, int n_in,
                              void* d_out, int out_size, void* d_ws, size_t ws_size,
                              hipStream_t stream) {
  const int*   positions = (const int*)d_in[0];
  const float* hidden    = (const float*)d_in[1];
  const float* w_qkv     = (const float*)d_in[3];
  const float* b_qkv     = (const float*)d_in[4];
  const float* q_norm_w  = (const float*)d_in[5];
  const float* k_norm_w  = (const float*)d_in[6];
  const float* w_o       = (const float*)d_in[7];
  float* out = (float*)d_out;
  const int T = in_sizes[0];
  const int noise = out_size / HID;
  const int ctx = T - noise;

  char* ws = (char*)d_ws;
  // layout (with aliasing): qkv_f32 [T*6144 f32] (later reused as attn_out bf16)
  float* qkv_f32 = (float*)ws;
  unsigned short* attn_out = (unsigned short*)ws;           // alias, used after qkv dead
  size_t off = (size_t)T * NQKV * 4;
  unsigned short* Hbf = (unsigned short*)(ws + off);        // T*HID bf16
  unsigned short* WoT = Hbf;                                // alias, written after QKV GEMM
  off += (size_t)T * HID * 2;
  unsigned short* WqkvT = (unsigned short*)(ws + off);      // NQKV*HID bf16
  off += (size_t)NQKV * HID * 2;
  float* cosT = (float*)(ws + off); off += (size_t)T * 64 * 4;
  float* sinT = (float*)(ws + off); off += (size_t)T * 64 * 4;
  unsigned short* Qb  = (unsigned short*)(ws + off); off += (size_t)NH * noise * HD * 2;
  unsigned short* Kbf = (unsigned short*)(ws + off); off += (size_t)NKV * T * HD * 2;
  unsigned short* Vtb = (unsigned short*)(ws + off); off += (size_t)NKV * HD * T * 2;

  ropetab<<<dim3(T), dim3(64), 0, stream>>>(positions, cosT, sinT);
  convbf<<<dim3(2048), dim3(256), 0, stream>>>(hidden, Hbf, (long)T * HID / 4);
  wtrans<<<dim3(NQKV / 64, HID / 64), dim3(256), 0, stream>>>(w_qkv, WqkvT, HID, NQKV);
  gemm_bt<<<dim3(NQKV / 128, T / 128, 1), dim3(256), 0, stream>>>(Hbf, WqkvT, qkv_f32, b_qkv, T, NQKV, HID);
  wtrans<<<dim3(HID / 64, HID / 64), dim3(256), 0, stream>>>(w_o, WoT, HID, HID);
  norm_rope<<<dim3(T), dim3(256), 0, stream>>>(qkv_f32, q_norm_w, k_norm_w, cosT, sinT, Qb, Kbf, T, ctx, noise);
  vtrans<<<dim3(T / 64, HD / 64, NKV), dim3(256), 0, stream>>>(qkv_f32, Vtb, T);
  const float scale = 0.08838834764831845f;  // HD^-0.5
  attn_kernel<<<dim3(noise / 64, NH), dim3(256), 0, stream>>>(Qb, Kbf, Vtb, attn_out, noise, T, scale);
  // split-K=2 out-projection: zero C, then atomicAdd partials (2x blocks in flight)
  hipMemsetAsync(d_out, 0, (size_t)out_size * sizeof(float), stream);
  gemm_bt<<<dim3(HID / 128, noise / 128, 2), dim3(256), 0, stream>>>(attn_out, WoT, out, (const float*)nullptr, noise, HID, HID);
}

// Round 3
// 643.461 us; speedup vs baseline: 1.3913x; 1.2489x over previous
//
#include <hip/hip_runtime.h>
#include <stdint.h>

#define NH 32
#define NKV 8
#define HD 128
#define HID 4096
#define NQKV 6144   // Q_SIZE + 2*KV_SIZE

typedef __attribute__((ext_vector_type(8))) __bf16 bf16x8;
typedef __attribute__((ext_vector_type(4))) float f32x4;
typedef __attribute__((ext_vector_type(4))) float float4v;
typedef __attribute__((ext_vector_type(8))) unsigned short ushort8v;
typedef __attribute__((ext_vector_type(4))) unsigned short ushort4v;
typedef __attribute__((ext_vector_type(2))) unsigned short ushort2v;

__device__ __forceinline__ unsigned short f2bf(float f) {
  union { float f; unsigned u; } x; x.f = f;
  unsigned r = x.u + 0x7fffu + ((x.u >> 16) & 1u);
  return (unsigned short)(r >> 16);
}

__device__ __forceinline__ void gld16(const void* g, void* l) {
  __builtin_amdgcn_global_load_lds(
      (const __attribute__((address_space(1))) unsigned int*)g,
      (__attribute__((address_space(3))) unsigned int*)l, 16, 0, 0);
}

__device__ __forceinline__ f32x4 mfma16(bf16x8 a, bf16x8 b, f32x4 c) {
  return __builtin_amdgcn_mfma_f32_16x16x32_bf16(a, b, c, 0, 0, 0);
}

// ---------------- RoPE table: cos/sin[t][64] (double-precision trig) ------
__global__ void ropetab(const int* __restrict__ pos, float* __restrict__ cosT,
                        float* __restrict__ sinT) {
  const int t = blockIdx.x, f = threadIdx.x;   // 64 threads
  const double inv = exp(-0.2158673524681918 * (double)f);  // ln(1e6)/64
  const double arg = (double)pos[t] * inv;
  cosT[t * 64 + f] = (float)cos(arg);
  sinT[t * 64 + f] = (float)sin(arg);
}

// ---------------- fp32 -> bf16 convert (no transpose) ---------------------
__global__ void convbf(const float* __restrict__ src, unsigned short* __restrict__ dst,
                       long n4) {
  long i = (long)blockIdx.x * blockDim.x + threadIdx.x;
  const long stride = (long)gridDim.x * blockDim.x;
  for (; i < n4; i += stride) {
    float4v v = *(const float4v*)(src + i * 4);
    ushort4v o;
    o.x = f2bf(v.x); o.y = f2bf(v.y); o.z = f2bf(v.z); o.w = f2bf(v.w);
    *(ushort4v*)(dst + i * 4) = o;
  }
}

// ------------- weight transpose+convert: W (K x N f32) -> Wt (N x K bf16) --
__global__ __launch_bounds__(256) void wtrans(const float* __restrict__ W,
                                              unsigned short* __restrict__ Wt,
                                              int K, int N) {
  __shared__ float tile[64][65];
  const int k0 = blockIdx.y * 64, n0 = blockIdx.x * 64;
  const int tid = threadIdx.x;
  const int rk = tid >> 4, cn = (tid & 15) * 4;
#pragma unroll
  for (int rr = 0; rr < 64; rr += 16) {
    float4v v = *(const float4v*)(W + (long)(k0 + rk + rr) * N + n0 + cn);
    tile[rk + rr][cn] = v.x; tile[rk + rr][cn + 1] = v.y;
    tile[rk + rr][cn + 2] = v.z; tile[rk + rr][cn + 3] = v.w;
  }
  __syncthreads();
  const int rn = tid >> 3, ck = (tid & 7) * 8;
#pragma unroll
  for (int rr = 0; rr < 64; rr += 32) {
    ushort8v o;
#pragma unroll
    for (int j = 0; j < 8; ++j) o[j] = f2bf(tile[ck + j][rn + rr]);
    *(ushort8v*)(Wt + (long)(n0 + rn + rr) * K + k0 + ck) = o;
  }
}

// ------------- V transpose: qkv f32 rows -> Vt[kvh][d][t] bf16 ------------
__global__ __launch_bounds__(256) void vtrans(const float* __restrict__ qkv,
                                              unsigned short* __restrict__ Vt, int T) {
  __shared__ float tile[64][65];
  const int kvh = blockIdx.z;
  const int t0 = blockIdx.x * 64, d0 = blockIdx.y * 64;
  const int tid = threadIdx.x;
  const int rt = tid >> 4, cd = (tid & 15) * 4;
#pragma unroll
  for (int rr = 0; rr < 64; rr += 16) {
    float4v v = *(const float4v*)(qkv + (long)(t0 + rt + rr) * NQKV + 5120 + kvh * 128 + d0 + cd);
    tile[rt + rr][cd] = v.x; tile[rt + rr][cd + 1] = v.y;
    tile[rt + rr][cd + 2] = v.z; tile[rt + rr][cd + 3] = v.w;
  }
  __syncthreads();
  const int rd = tid >> 3, ct = (tid & 7) * 8;
#pragma unroll
  for (int rr = 0; rr < 64; rr += 32) {
    ushort8v o;
#pragma unroll
    for (int j = 0; j < 8; ++j) o[j] = f2bf(tile[ct + j][rd + rr]);
    *(ushort8v*)(Vt + ((long)kvh * 128 + d0 + rd + rr) * T + t0 + ct) = o;
  }
}

// ------------- RMSNorm + RoPE: qkv f32 -> Q/K bf16 ------------------------
__global__ __launch_bounds__(256) void norm_rope(
    const float* __restrict__ qkv, const float* __restrict__ qw,
    const float* __restrict__ kw, const float* __restrict__ cosT,
    const float* __restrict__ sinT, unsigned short* __restrict__ Qo,
    unsigned short* __restrict__ Ko, int T, int ctx, int noise) {
  const int t = blockIdx.x;
  __shared__ float cs[64], sn[64];
  const int tid = threadIdx.x;
  if (tid < 64) { cs[tid] = cosT[t * 64 + tid]; sn[tid] = sinT[t * 64 + tid]; }
  __syncthreads();
  const int wid = tid >> 6, lane = tid & 63;
  const float* row = qkv + (long)t * NQKV;
  const bool isNoise = (t >= ctx);
  for (int sl = wid; sl < 40; sl += 4) {      // slots: 0-31 q heads, 32-39 k heads
    if (sl < 32 && !isNoise) continue;
    const float* x = row + sl * 128;
    float v0 = x[lane * 2], v1 = x[lane * 2 + 1];
    float ss = v0 * v0 + v1 * v1;
#pragma unroll
    for (int off = 32; off >= 1; off >>= 1) ss += __shfl_xor(ss, off);
    const float rinv = rsqrtf(ss * (1.f / 128.f) + 1e-6f);
    const float* w = (sl < 32) ? qw : kw;
    v0 *= rinv * w[lane * 2];
    v1 *= rinv * w[lane * 2 + 1];
    const float p0 = __shfl_xor(v0, 32);
    const float p1 = __shfl_xor(v1, 32);
    const int f0 = (lane * 2) & 63, f1 = (lane * 2 + 1) & 63;
    float o0, o1;
    if (lane < 32) { o0 = v0 * cs[f0] - p0 * sn[f0]; o1 = v1 * cs[f1] - p1 * sn[f1]; }
    else           { o0 = v0 * cs[f0] + p0 * sn[f0]; o1 = v1 * cs[f1] + p1 * sn[f1]; }
    ushort2v o; o.x = f2bf(o0); o.y = f2bf(o1);
    if (sl < 32)
      *(ushort2v*)(Qo + ((long)sl * noise + (t - ctx)) * 128 + lane * 2) = o;
    else
      *(ushort2v*)(Ko + ((long)(sl - 32) * T + t) * 128 + lane * 2) = o;
  }
}

// ------------- QKV GEMM, row-split (skips context Q columns) --------------
// A: T x 4096 bf16, Bt: 6144 x 4096 bf16, C: T x 6144 f32 (+bias)
// Region 0 (context rows):  rows [0,ctx)   x cols [4096,6144)   (K/V only)
// Region 1 (noise rows):    rows [ctx,T)   x cols [0,6144)
// One launch; 2-phase double-buffered LDS pipeline; XCD-swizzled block idx.
__global__ __launch_bounds__(256) void gemm_qkv(
    const unsigned short* __restrict__ A, const unsigned short* __restrict__ Bt,
    float* __restrict__ C, const float* __restrict__ bias, int ctx, int nKV) {
  __shared__ unsigned short As[2][128 * 32];
  __shared__ unsigned short Bs[2][128 * 32];
  const int K = HID;
  const int tid = threadIdx.x;
  const int wid = tid >> 6, lane = tid & 63;
  const int lr = lane & 15, lg = lane >> 4;
  // XCD swizzle (gridDim.x % 8 == 0)
  const int cpx = gridDim.x >> 3;
  const int swz = (blockIdx.x & 7) * cpx + (blockIdx.x >> 3);
  long bm, bn;
  if (swz < nKV) {
    bm = (long)(swz / 16) * 128;
    bn = 4096 + (long)(swz % 16) * 128;
  } else {
    const int r = swz - nKV;
    bm = ctx + (long)(r / 48) * 128;
    bn = (long)(r % 48) * 128;
  }
  const int wm = (wid >> 1) * 64;
  const int wn = (wid & 1) * 64;
  f32x4 acc[4][4] = {};

  const int r0 = (wid * 64 + lane) >> 2;           // staging row this lane owns (c=0)
  const int ce0 = ((wid * 64 + lane) & 3) * 8;
  const int r1 = ((4 + wid) * 64 + lane) >> 2;     // c=1
  const int ce1 = (((4 + wid) * 64 + lane) & 3) * 8;

#define STAGE(buf, k0)                                                        \
  do {                                                                        \
    gld16(A + (bm + r0) * (long)K + (k0) + ce0, As[buf] + wid * 512);         \
    gld16(Bt + (bn + r0) * (long)K + (k0) + ce0, Bs[buf] + wid * 512);        \
    gld16(A + (bm + r1) * (long)K + (k0) + ce1, As[buf] + (4 + wid) * 512);   \
    gld16(Bt + (bn + r1) * (long)K + (k0) + ce1, Bs[buf] + (4 + wid) * 512);  \
  } while (0)

#define COMPUTE(buf)                                                          \
  do {                                                                        \
    bf16x8 af[4], bfv[4];                                                     \
    _Pragma("unroll") for (int i = 0; i < 4; ++i) {                           \
      af[i]  = *(const bf16x8*)(As[buf] + (wm + i * 16 + lr) * 32 + lg * 8);  \
      bfv[i] = *(const bf16x8*)(Bs[buf] + (wn + i * 16 + lr) * 32 + lg * 8);  \
    }                                                                         \
    _Pragma("unroll") for (int i = 0; i < 4; ++i)                             \
      _Pragma("unroll") for (int j = 0; j < 4; ++j)                           \
        acc[i][j] = mfma16(af[i], bfv[j], acc[i][j]);                         \
  } while (0)

  STAGE(0, 0);
  __syncthreads();
  int cur = 0;
  for (int k0 = 32; k0 < K; k0 += 32) {
    STAGE(cur ^ 1, k0);
    COMPUTE(cur);
    __syncthreads();
    cur ^= 1;
  }
  COMPUTE(cur);

#pragma unroll
  for (int i = 0; i < 4; ++i) {
#pragma unroll
    for (int j = 0; j < 4; ++j) {
      const long row = bm + wm + i * 16 + lg * 4;
      const long col = bn + wn + j * 16 + lr;
      const float b = bias[col];
#pragma unroll
      for (int r = 0; r < 4; ++r)
        C[(row + r) * (long)NQKV + col] = acc[i][j][r] + b;
    }
  }
}

// ------------- generic bf16 GEMM: C = A @ Bt^T, split-K partial stores -----
// A: M x K bf16, Bt: N x K bf16. gridDim.z partials written to C[z*M*N + ...]
__global__ __launch_bounds__(256) void gemm_bt(
    const unsigned short* __restrict__ A, const unsigned short* __restrict__ Bt,
    float* __restrict__ C, int M, int N, int K) {
  __shared__ unsigned short As[2][128 * 32];
  __shared__ unsigned short Bs[2][128 * 32];
  const int tid = threadIdx.x;
  const int wid = tid >> 6, lane = tid & 63;
  const int lr = lane & 15, lg = lane >> 4;
  const long bm = (long)blockIdx.y * 128;
  const long bn = (long)blockIdx.x * 128;
  const int wm = (wid >> 1) * 64;
  const int wn = (wid & 1) * 64;
  const int kLen = K / gridDim.z;
  const int kOff = blockIdx.z * kLen;
  float* Cz = C + (size_t)blockIdx.z * M * N;
  f32x4 acc[4][4] = {};

  const int r0 = (wid * 64 + lane) >> 2;
  const int ce0 = ((wid * 64 + lane) & 3) * 8;
  const int r1 = ((4 + wid) * 64 + lane) >> 2;
  const int ce1 = (((4 + wid) * 64 + lane) & 3) * 8;

  STAGE(0, kOff);
  __syncthreads();
  int cur = 0;
  for (int k0 = kOff + 32; k0 < kOff + kLen; k0 += 32) {
    STAGE(cur ^ 1, k0);
    COMPUTE(cur);
    __syncthreads();
    cur ^= 1;
  }
  COMPUTE(cur);

#pragma unroll
  for (int i = 0; i < 4; ++i) {
#pragma unroll
    for (int j = 0; j < 4; ++j) {
      const long row = bm + wm + i * 16 + lg * 4;
      const long col = bn + wn + j * 16 + lr;
#pragma unroll
      for (int r = 0; r < 4; ++r)
        Cz[(row + r) * (long)N + col] = acc[i][j][r];
    }
  }
}

// ------------- sum 4 split-K partials ------------------------------------
__global__ void reduce4(const float* __restrict__ P, float* __restrict__ out,
                        long n4, long stride) {
  long i = (long)blockIdx.x * blockDim.x + threadIdx.x;
  const long gs = (long)gridDim.x * blockDim.x;
  for (; i < n4; i += gs) {
    float4v a = *(const float4v*)(P + i * 4);
    float4v b = *(const float4v*)(P + stride + i * 4);
    float4v c = *(const float4v*)(P + 2 * stride + i * 4);
    float4v d = *(const float4v*)(P + 3 * stride + i * 4);
    float4v o = a + b + c + d;
    *(float4v*)(out + i * 4) = o;
  }
}

// ------------- flash attention (GQA, full non-causal) ---------------------
// Q: [NH][noise][128], K: [NKV][T][128], Vt: [NKV][128][T], O: [noise][4096] bf16
// All LDS tiles XOR-swizzled: logical 16B chunk c in row r lives at c^(r&7).
__global__ __launch_bounds__(256) void attn_kernel(
    const unsigned short* __restrict__ Q, const unsigned short* __restrict__ Kb,
    const unsigned short* __restrict__ Vt, unsigned short* __restrict__ Oout,
    int noise, int T, float scale) {
  __shared__ unsigned short Ks[64 * 128];   // [t][d], swizzled
  __shared__ unsigned short Vs[128 * 64];   // [d][t], swizzled
  __shared__ unsigned short Ps[4 * 16 * 64];// per-wave [16][64], swizzled
  const int h = blockIdx.y;
  const int kvh = h >> 2;
  const int tid = threadIdx.x, wid = tid >> 6, lane = tid & 63;
  const int lr = lane & 15, lg = lane >> 4;
  const unsigned short* qb = Q + ((long)h * noise + blockIdx.x * 64 + wid * 16 + lr) * 128;
  bf16x8 qf[4];
#pragma unroll
  for (int kc = 0; kc < 4; ++kc) qf[kc] = *(const bf16x8*)(qb + kc * 32 + lg * 8);
  const unsigned short* kbase = Kb + (long)kvh * T * 128;
  const unsigned short* vbase = Vt + (long)kvh * 128 * T;
  f32x4 accO[8] = {};
  float m_r[4], l_r[4];
#pragma unroll
  for (int r = 0; r < 4; ++r) { m_r[r] = -1e30f; l_r[r] = 0.f; }
  unsigned short* pw = Ps + wid * 1024;
  const int sw = (lr & 7) << 3;             // read-side XOR (shorts)
  for (int t0 = 0; t0 < T; t0 += 64) {
#pragma unroll
    for (int c = 0; c < 4; ++c) {
      const int q = c * 4 + wid;
      const int idx = q * 64 + lane;
      const int kgi = (idx & ~7) | ((idx ^ (idx >> 4)) & 7);
      gld16(kbase + (long)t0 * 128 + (long)kgi * 8, Ks + q * 512);
      const int d = idx >> 3;
      const int cg = (idx ^ d) & 7;
      gld16(vbase + (long)d * T + t0 + cg * 8, Vs + q * 512);
    }
    __syncthreads();
    f32x4 s[4] = {};
    __builtin_amdgcn_s_setprio(1);
#pragma unroll
    for (int kc = 0; kc < 4; ++kc)
#pragma unroll
      for (int nt = 0; nt < 4; ++nt) {
        bf16x8 kf = *(const bf16x8*)(Ks + (nt * 16 + lr) * 128 + (((kc * 32) + lg * 8) ^ sw));
        s[nt] = mfma16(qf[kc], kf, s[nt]);
      }
    __builtin_amdgcn_s_setprio(0);
#pragma unroll
    for (int nt = 0; nt < 4; ++nt)
#pragma unroll
      for (int r = 0; r < 4; ++r) s[nt][r] *= scale;
    float mt[4], rs[4];
#pragma unroll
    for (int r = 0; r < 4; ++r)
      mt[r] = fmaxf(fmaxf(s[0][r], s[1][r]), fmaxf(s[2][r], s[3][r]));
#pragma unroll
    for (int off = 8; off >= 1; off >>= 1)
#pragma unroll
      for (int r = 0; r < 4; ++r) mt[r] = fmaxf(mt[r], __shfl_xor(mt[r], off));
    float corr[4];
#pragma unroll
    for (int r = 0; r < 4; ++r) {
      const float mn = fmaxf(m_r[r], mt[r]);
      corr[r] = __expf(m_r[r] - mn);
      m_r[r] = mn;
      rs[r] = 0.f;
    }
#pragma unroll
    for (int nt = 0; nt < 4; ++nt)
#pragma unroll
      for (int r = 0; r < 4; ++r) {
        const float p = __expf(s[nt][r] - m_r[r]);
        s[nt][r] = p;
        rs[r] += p;
      }
#pragma unroll
    for (int off = 8; off >= 1; off >>= 1)
#pragma unroll
      for (int r = 0; r < 4; ++r) rs[r] += __shfl_xor(rs[r], off);
#pragma unroll
    for (int r = 0; r < 4; ++r) l_r[r] = l_r[r] * corr[r] + rs[r];
#pragma unroll
    for (int nd = 0; nd < 8; ++nd)
#pragma unroll
      for (int r = 0; r < 4; ++r) accO[nd][r] *= corr[r];
#pragma unroll
    for (int nt = 0; nt < 4; ++nt)
#pragma unroll
      for (int r = 0; r < 4; ++r) {
        const int prow = lg * 4 + r;
        pw[prow * 64 + ((nt * 16 + lr) ^ ((prow & 7) << 3))] = f2bf(s[nt][r]);
      }
    __syncthreads();
    __builtin_amdgcn_s_setprio(1);
#pragma unroll
    for (int kc = 0; kc < 2; ++kc) {
      bf16x8 pa = *(const bf16x8*)(pw + lr * 64 + (((kc * 32) + lg * 8) ^ sw));
#pragma unroll
      for (int nd = 0; nd < 8; ++nd) {
        bf16x8 vf = *(const bf16x8*)(Vs + (nd * 16 + lr) * 64 + (((kc * 32) + lg * 8) ^ sw));
        accO[nd] = mfma16(pa, vf, accO[nd]);
      }
    }
    __builtin_amdgcn_s_setprio(0);
    __syncthreads();
  }
  float inv[4];
#pragma unroll
  for (int r = 0; r < 4; ++r) inv[r] = 1.f / l_r[r];
  const long orow = (long)blockIdx.x * 64 + wid * 16;
#pragma unroll
  for (int nd = 0; nd < 8; ++nd)
#pragma unroll
    for (int r = 0; r < 4; ++r)
      Oout[(orow + lg * 4 + r) * 4096 + h * 128 + nd * 16 + lr] =
          f2bf(accO[nd][r] * inv[r]);
}

extern "C" void kernel_launch(void* const* d_in, const int* in_sizes, int n_in,
                              void* d_out, int out_size, void* d_ws, size_t ws_size,
                              hipStream_t stream) {
  const int*   positions = (const int*)d_in[0];
  const float* hidden    = (const float*)d_in[1];
  const float* w_qkv     = (const float*)d_in[3];
  const float* b_qkv     = (const float*)d_in[4];
  const float* q_norm_w  = (const float*)d_in[5];
  const float* k_norm_w  = (const float*)d_in[6];
  const float* w_o       = (const float*)d_in[7];
  float* out = (float*)d_out;
  const int T = in_sizes[0];
  const int noise = out_size / HID;
  const int ctx = T - noise;

  char* ws = (char*)d_ws;
  // region0: qkv_f32 [T*6144 f32] — later dead; start aliased as attn_out bf16,
  // bytes [16MB, 16MB+4*noise*HID*4) aliased as split-K partials.
  float* qkv_f32 = (float*)ws;
  unsigned short* attn_out = (unsigned short*)ws;
  float* Cpart = (float*)(ws + (size_t)16 * 1024 * 1024);
  size_t off = (size_t)T * NQKV * 4;
  unsigned short* Hbf = (unsigned short*)(ws + off);        // T*HID bf16
  unsigned short* WoT = Hbf;                                // alias, written after QKV GEMM
  off += (size_t)T * HID * 2;
  unsigned short* WqkvT = (unsigned short*)(ws + off);      // NQKV*HID bf16
  off += (size_t)NQKV * HID * 2;
  float* cosT = (float*)(ws + off); off += (size_t)T * 64 * 4;
  float* sinT = (float*)(ws + off); off += (size_t)T * 64 * 4;
  unsigned short* Qb  = (unsigned short*)(ws + off); off += (size_t)NH * noise * HD * 2;
  unsigned short* Kbf = (unsigned short*)(ws + off); off += (size_t)NKV * T * HD * 2;
  unsigned short* Vtb = (unsigned short*)(ws + off); off += (size_t)NKV * HD * T * 2;

  ropetab<<<dim3(T), dim3(64), 0, stream>>>(positions, cosT, sinT);
  convbf<<<dim3(2048), dim3(256), 0, stream>>>(hidden, Hbf, (long)T * HID / 4);
  wtrans<<<dim3(NQKV / 64, HID / 64), dim3(256), 0, stream>>>(w_qkv, WqkvT, HID, NQKV);
  const int nKV = (2048 / 128) * (ctx / 128);          // context-row KV blocks
  const int nNoise = (NQKV / 128) * (noise / 128);     // noise-row full blocks
  gemm_qkv<<<dim3(nKV + nNoise), dim3(256), 0, stream>>>(Hbf, WqkvT, qkv_f32, b_qkv, ctx, nKV);
  wtrans<<<dim3(HID / 64, HID / 64), dim3(256), 0, stream>>>(w_o, WoT, HID, HID);
  norm_rope<<<dim3(T), dim3(256), 0, stream>>>(qkv_f32, q_norm_w, k_norm_w, cosT, sinT, Qb, Kbf, T, ctx, noise);
  vtrans<<<dim3(T / 64, HD / 64, NKV), dim3(256), 0, stream>>>(qkv_f32, Vtb, T);
  const float scale = 0.08838834764831845f;  // HD^-0.5
  attn_kernel<<<dim3(noise / 64, NH), dim3(256), 0, stream>>>(Qb, Kbf, Vtb, attn_out, noise, T, scale);
  // split-K=4 out-projection into partial buffers (dead qkv_f32 region), then reduce
  gemm_bt<<<dim3(HID / 128, noise / 128, 4), dim3(256), 0, stream>>>(attn_out, WoT, Cpart, noise, HID, HID);
  reduce4<<<dim3(1024), dim3(256), 0, stream>>>(Cpart, out, (long)noise * HID / 4, (long)noise * HID);
}